// Round 12
// baseline (718.834 us; speedup 1.0000x reference)
//
#include <hip/hip_runtime.h>
#include <hip/hip_bf16.h>

#define N_TOK 16384
#define H_DIM 768
#define I_DIM 3072
#define NEXP 8
#define RBLK 1024   // router grid: 16 contiguous tokens per block; rank depends on this

typedef short bf16x8 __attribute__((ext_vector_type(8)));
typedef float f32x4 __attribute__((ext_vector_type(4)));

__device__ __forceinline__ unsigned short f2bf(float f) {
    unsigned int u = __float_as_uint(f);
    u += 0x7fffu + ((u >> 16) & 1u);
    return (unsigned short)(u >> 16);
}

__device__ __forceinline__ float gelu_tanh(float v) {
    float u = 0.7978845608028654f * (v + 0.044715f * v * v * v);
    float t = __expf(2.0f * fminf(u, 15.0f));
    return 0.5f * v * (1.0f + (t - 1.0f) / (t + 1.0f));
}

__device__ __forceinline__ void gll16(const void* g, void* l) {
    __builtin_amdgcn_global_load_lds(
        (const __attribute__((address_space(1))) unsigned int*)g,
        (__attribute__((address_space(3))) unsigned int*)l, 16, 0, 0);
}

// ---------------- Router: contiguous 16-token strip per block ----------------
__global__ __launch_bounds__(256) void moe_router(
    const float* __restrict__ x, const float* __restrict__ gw,
    unsigned short* __restrict__ xbf,
    int* __restrict__ topidx, float* __restrict__ topw,
    float* __restrict__ partials)
{
    __shared__ float gws[NEXP * H_DIM];  // 24 KB
    __shared__ float red[64];
    const int tid = threadIdx.x;
    for (int i = tid * 4; i < NEXP * H_DIM; i += 1024)
        *(float4*)(gws + i) = *(const float4*)(gw + i);
    __syncthreads();

    const int lane = tid & 63;
    const int wid = tid >> 6;
    const int tbase = blockIdx.x * 16 + wid * 4;

    float lcnt[8], lps[8];
#pragma unroll
    for (int e = 0; e < 8; ++e) { lcnt[e] = 0.f; lps[e] = 0.f; }

#pragma unroll
    for (int k = 0; k < 4; ++k) {
        const int t = tbase + k;
        float acc[8] = {0.f, 0.f, 0.f, 0.f, 0.f, 0.f, 0.f, 0.f};
#pragma unroll
        for (int j = 0; j < 3; ++j) {
            const int col = j * 256 + lane * 4;
            float4 xv = *(const float4*)(x + (size_t)t * H_DIM + col);
            ushort4 o;
            o.x = f2bf(xv.x); o.y = f2bf(xv.y); o.z = f2bf(xv.z); o.w = f2bf(xv.w);
            *(ushort4*)(xbf + (size_t)t * H_DIM + col) = o;
#pragma unroll
            for (int e = 0; e < 8; ++e) {
                float4 g = *(const float4*)(gws + e * H_DIM + col);
                acc[e] += xv.x * g.x + xv.y * g.y + xv.z * g.z + xv.w * g.w;
            }
        }
#pragma unroll
        for (int off = 32; off >= 1; off >>= 1)
#pragma unroll
            for (int e = 0; e < 8; ++e) acc[e] += __shfl_xor(acc[e], off, 64);

        int e0 = 0;
#pragma unroll
        for (int e = 1; e < 8; ++e) if (acc[e] > acc[e0]) e0 = e;
        int e1 = (e0 == 0) ? 1 : 0;
#pragma unroll
        for (int e = 0; e < 8; ++e) if (e != e0 && acc[e] > acc[e1]) e1 = e;

        float mx = acc[0];
#pragma unroll
        for (int e = 1; e < 8; ++e) mx = fmaxf(mx, acc[e]);
        float p[8]; float s = 0.f;
#pragma unroll
        for (int e = 0; e < 8; ++e) { p[e] = expf(acc[e] - mx); s += p[e]; }
        float inv = 1.0f / s;
#pragma unroll
        for (int e = 0; e < 8; ++e) p[e] *= inv;

        float wsum = p[e0] + p[e1];
        if (lane == 0) {
            topidx[2 * t] = e0; topidx[2 * t + 1] = e1;
            topw[2 * t] = p[e0] / wsum; topw[2 * t + 1] = p[e1] / wsum;
            lcnt[e0] += 1.f; lcnt[e1] += 1.f;
#pragma unroll
            for (int e = 0; e < 8; ++e) lps[e] += p[e];
        }
    }

    if (lane == 0) {
#pragma unroll
        for (int e = 0; e < 8; ++e) {
            red[wid * 16 + e] = lcnt[e];
            red[wid * 16 + 8 + e] = lps[e];
        }
    }
    __syncthreads();
    if (tid < 16)
        partials[blockIdx.x * 16 + tid] =
            red[tid] + red[16 + tid] + red[32 + tid] + red[48 + tid];
}

// ------- fused rank (+offsets +aux): one block per 16-token strip -------
__global__ __launch_bounds__(256) void moe_rank(
    const int* __restrict__ topidx, const float* __restrict__ topw,
    const float* __restrict__ partials, int* __restrict__ offs,
    float* __restrict__ aux_out, int* __restrict__ perm, float* __restrict__ pw)
{
    const int b = blockIdx.x;
    const int tid = threadIdx.x;
    __shared__ float stot[256], spre[256];
    __shared__ float tot[16];
    __shared__ int pfx[8];

    const int c = tid & 15;
    float vtot = 0.f, vpre = 0.f;
    for (int r = tid >> 4; r < RBLK; r += 16) {
        float v = partials[r * 16 + c];
        vtot += v;
        if (r < b) vpre += v;
    }
    stot[tid] = vtot; spre[tid] = vpre;
    __syncthreads();
    if (tid < 16) {
        float t = 0.f, q = 0.f;
#pragma unroll
        for (int k = 0; k < 16; ++k) { t += stot[k * 16 + tid]; q += spre[k * 16 + tid]; }
        tot[tid] = t;
        if (tid < 8) spre[tid] = q;   // reuse: per-expert prefix for this strip
    }
    __syncthreads();
    if (tid == 0) {
        int run = 0;
        float aux = 0.f;
#pragma unroll
        for (int e = 0; e < 8; ++e) {
            pfx[e] = run + (int)(spre[e] + 0.5f);
            aux += (tot[e] / (float)(N_TOK * 2)) * (tot[8 + e] / (float)N_TOK);
            if (b == 0) offs[e] = run;
            run += (int)(tot[e] + 0.5f);
        }
        if (b == 0) { offs[8] = run; *aux_out = 0.01f * 8.0f * aux; }
    }
    __syncthreads();
    if (tid < 32) {
        const int t = b * 16 + (tid >> 1);
        const int slot = tid & 1;
        const int myexp = topidx[2 * t + slot];
        int rank = 0;
#pragma unroll
        for (int ee = 0; ee < 8; ++ee) {
            unsigned long long m = __ballot(myexp == ee);
            if (myexp == ee)
                rank = pfx[ee] + __popcll(m & ((1ull << tid) - 1ull));
        }
        perm[rank] = t;
        pw[rank] = topw[2 * t + slot];
    }
}

// ---------------- fused fp32 -> bf16 convert of w1 and w2 ----------------
__global__ __launch_bounds__(256) void moe_cvt2(
    const float* __restrict__ a, unsigned short* __restrict__ oa,
    const float* __restrict__ bsrc, unsigned short* __restrict__ ob, int n)
{
    int idx = (blockIdx.x * 256 + threadIdx.x) * 4;
    const int stride = gridDim.x * 1024;
    for (; idx < 2 * n; idx += stride) {
        const float* in = (idx < n) ? a : bsrc;
        unsigned short* out = (idx < n) ? oa : ob;
        const int i = (idx < n) ? idx : idx - n;
        float4 v = *(const float4*)(in + i);
        ushort4 o;
        o.x = f2bf(v.x); o.y = f2bf(v.y); o.z = f2bf(v.z); o.w = f2bf(v.w);
        *(ushort4*)(out + i) = o;
    }
}

// ====== 256x256 / 8-wave / BK=32 / 4-slot counted-vmcnt / 2-phase GEMM core ======
// Slot algebra and staging: verbatim R10 (HW-verified). Schedule change: each
// BK=32 tile is split into 2 phases. ph0: {read B0-3 + A0-3 (8 ds_read), stage
// A-half of t+3} -> barrier -> setprio 16 MFMA(i=0..3) -> barrier. ph1: {read
// A4-7, stage B-half of t+3, vmcnt(8)} -> barrier -> 16 MFMA(i=4..7) -> barrier.
// vmcnt(8) = 2 tiles in flight (retires t+1); never 0 in main loop; tail peels
// vmcnt(4)/vmcnt(0)/none (R10-verified counts). Stage writes slot (t+3)&3 =
// (t-1)&3, whose last reads completed before tile t-1's final barrier.

#define MFMA_(d_, va_, vb_) d_ = __builtin_amdgcn_mfma_f32_16x16x32_bf16(va_, vb_, d_, 0, 0, 0)
#define BAR asm volatile("s_barrier" ::: "memory")
#define SCHED0 __builtin_amdgcn_sched_barrier(0)

#define STAGE_A2(tt) { unsigned short* D_ = As + ((tt) & 3) * 8192;               \
      gll16(asrc0 + (tt) * 32, D_ + tid * 8);                                     \
      gll16(asrc1 + (tt) * 32, D_ + 4096 + tid * 8); }
#define STAGE_B2(tt) { unsigned short* D_ = Bs + ((tt) & 3) * 8192;               \
      gll16(bsrc0 + (tt) * 32, D_ + tid * 8);                                     \
      gll16(bsrc1 + (tt) * 32, D_ + 4096 + tid * 8); }

#define VM8  asm volatile("s_waitcnt vmcnt(8)" ::: "memory")
#define VM4  asm volatile("s_waitcnt vmcnt(4)" ::: "memory")
#define VM0  asm volatile("s_waitcnt vmcnt(0)" ::: "memory")
#define VMNONE (void)0

#define GEMM_TILE(t, SA_OP, SB_OP, VM_OP)                                         \
  { const unsigned short* Ab_ = As + ((t) & 3) * 8192 + pAoff;                    \
    const unsigned short* Bb_ = Bs + ((t) & 3) * 8192 + pBoff;                    \
    bf16x8 b0 = *(const bf16x8*)(Bb_ + 0 * 1024);                                 \
    bf16x8 b1 = *(const bf16x8*)(Bb_ + 1 * 1024);                                 \
    bf16x8 b2 = *(const bf16x8*)(Bb_ + 2 * 1024);                                 \
    bf16x8 b3 = *(const bf16x8*)(Bb_ + 3 * 1024);                                 \
    bf16x8 a0 = *(const bf16x8*)(Ab_ + 0 * 1024);                                 \
    bf16x8 a1 = *(const bf16x8*)(Ab_ + 1 * 1024);                                 \
    bf16x8 a2 = *(const bf16x8*)(Ab_ + 2 * 1024);                                 \
    bf16x8 a3 = *(const bf16x8*)(Ab_ + 3 * 1024);                                 \
    SA_OP;                                                                        \
    BAR; SCHED0;                                                                  \
    __builtin_amdgcn_s_setprio(1);                                                \
    MFMA_(acc[0][0],a0,b0); MFMA_(acc[0][1],a0,b1); MFMA_(acc[0][2],a0,b2); MFMA_(acc[0][3],a0,b3); \
    MFMA_(acc[1][0],a1,b0); MFMA_(acc[1][1],a1,b1); MFMA_(acc[1][2],a1,b2); MFMA_(acc[1][3],a1,b3); \
    MFMA_(acc[2][0],a2,b0); MFMA_(acc[2][1],a2,b1); MFMA_(acc[2][2],a2,b2); MFMA_(acc[2][3],a2,b3); \
    MFMA_(acc[3][0],a3,b0); MFMA_(acc[3][1],a3,b1); MFMA_(acc[3][2],a3,b2); MFMA_(acc[3][3],a3,b3); \
    __builtin_amdgcn_s_setprio(0);                                                \
    BAR;                                                                          \
    a0 = *(const bf16x8*)(Ab_ + 4 * 1024);                                        \
    a1 = *(const bf16x8*)(Ab_ + 5 * 1024);                                        \
    a2 = *(const bf16x8*)(Ab_ + 6 * 1024);                                        \
    a3 = *(const bf16x8*)(Ab_ + 7 * 1024);                                        \
    SB_OP;                                                                        \
    VM_OP;                                                                        \
    BAR; SCHED0;                                                                  \
    __builtin_amdgcn_s_setprio(1);                                                \
    MFMA_(acc[4][0],a0,b0); MFMA_(acc[4][1],a0,b1); MFMA_(acc[4][2],a0,b2); MFMA_(acc[4][3],a0,b3); \
    MFMA_(acc[5][0],a1,b0); MFMA_(acc[5][1],a1,b1); MFMA_(acc[5][2],a1,b2); MFMA_(acc[5][3],a1,b3); \
    MFMA_(acc[6][0],a2,b0); MFMA_(acc[6][1],a2,b1); MFMA_(acc[6][2],a2,b2); MFMA_(acc[6][3],a2,b3); \
    MFMA_(acc[7][0],a3,b0); MFMA_(acc[7][1],a3,b1); MFMA_(acc[7][2],a3,b2); MFMA_(acc[7][3],a3,b3); \
    __builtin_amdgcn_s_setprio(0);                                                \
    BAR; }

#define GEMM_PIPELINE(NT)                                                         \
    STAGE_A2(0); STAGE_B2(0);                                                     \
    STAGE_A2(1); STAGE_B2(1);                                                     \
    STAGE_A2(2); STAGE_B2(2);                                                     \
    VM8; BAR;                                                                     \
    for (int t = 0; t < (NT) - 3; ++t)                                            \
        GEMM_TILE(t, STAGE_A2(t + 3), STAGE_B2(t + 3), VM8);                      \
    GEMM_TILE((NT) - 3, VMNONE, VMNONE, VM4);                                     \
    GEMM_TILE((NT) - 2, VMNONE, VMNONE, VM0);                                     \
    GEMM_TILE((NT) - 1, VMNONE, VMNONE, VMNONE);

// ---------------- GEMM1: h = gelu(gather(x) @ w1[e]^T) -> hbuf [rows][3072] ----
__global__ __launch_bounds__(512) void moe_gemm1(
    const unsigned short* __restrict__ xbf,
    const unsigned short* __restrict__ w1bf,
    const int* __restrict__ perm, const int* __restrict__ offs,
    unsigned short* __restrict__ hbuf, int e0)
{
    const int e = e0 + blockIdx.z;
    const int off = offs[e];
    const int n_e = offs[e + 1] - off;
    const int rt = blockIdx.y;
    if (rt * 256 >= n_e) return;
    const int ct = blockIdx.x;                   // 0..11
    const int coff = off - offs[e0];

    __shared__ __align__(16) unsigned short As[4 * 8192];  // 64 KB
    __shared__ __align__(16) unsigned short Bs[4 * 8192];  // 64 KB

    const int tid = threadIdx.x;
    const int lane = tid & 63;
    const int wid = tid >> 6;
    const int wm = wid >> 2, wn = wid & 3;       // wave tile 128x64

    // staging geometry (R10-verified)
    const int m = tid >> 3;                      // 0..63
    const int csw = (tid & 7) ^ (m & 7);
    const int hi = csw >> 2, kc = csw & 3;

    const unsigned short* asrc0; const unsigned short* asrc1;
    const unsigned short* bsrc0; const unsigned short* bsrc1;
    {
        int r0 = hi * 128 + m, r1 = r0 + 64;
        int lr0 = rt * 256 + r0; if (lr0 >= n_e) lr0 = n_e - 1;
        int lr1 = rt * 256 + r1; if (lr1 >= n_e) lr1 = n_e - 1;
        asrc0 = xbf + (size_t)perm[off + lr0] * H_DIM + kc * 8;
        asrc1 = xbf + (size_t)perm[off + lr1] * H_DIM + kc * 8;
        bsrc0 = w1bf + ((size_t)e * I_DIM + ct * 256 + r0) * H_DIM + kc * 8;
        bsrc1 = w1bf + ((size_t)e * I_DIM + ct * 256 + r1) * H_DIM + kc * 8;
    }

    const int pAoff = (lane & 15) * 64 + ((((wm << 2) | (lane >> 4)) ^ (lane & 7)) << 3);
    const int pBoff = (wn & 1) * 4096 + (lane & 15) * 64 +
                      (((((wn >> 1) << 2) | (lane >> 4)) ^ (lane & 7)) << 3);

    f32x4 acc[8][4] = {};

    GEMM_PIPELINE(H_DIM / 32);                   // NT = 24

    const int rbase = rt * 256 + wm * 128 + (lane >> 4) * 4;
    const int cbase = ct * 256 + wn * 64 + (lane & 15);
#pragma unroll
    for (int i = 0; i < 8; ++i) {
#pragma unroll
        for (int r = 0; r < 4; ++r) {
            const int lr = rbase + i * 16 + r;
            if (lr < n_e) {
                unsigned short* dst = hbuf + (size_t)(coff + lr) * I_DIM + cbase;
#pragma unroll
                for (int j = 0; j < 4; ++j)
                    dst[j * 16] = f2bf(gelu_tanh(acc[i][j][r]));
            }
        }
    }
}

// ---------------- GEMM2: y += w * (h @ w2[e]^T), full K=3072 ----------------
__global__ __launch_bounds__(512) void moe_gemm2(
    const unsigned short* __restrict__ hbuf,
    const unsigned short* __restrict__ w2bf,
    const int* __restrict__ perm, const float* __restrict__ pw,
    const int* __restrict__ offs, float* __restrict__ y, int e0)
{
    const int e = e0 + blockIdx.z;
    const int off = offs[e];
    const int n_e = offs[e + 1] - off;
    const int rt = blockIdx.y;
    if (rt * 256 >= n_e) return;
    const int ct = blockIdx.x;                   // 0..2
    const int coff = off - offs[e0];

    __shared__ __align__(16) unsigned short As[4 * 8192];
    __shared__ __align__(16) unsigned short Bs[4 * 8192];

    const int tid = threadIdx.x;
    const int lane = tid & 63;
    const int wid = tid >> 6;
    const int wm = wid >> 2, wn = wid & 3;

    const int m = tid >> 3;
    const int csw = (tid & 7) ^ (m & 7);
    const int hi = csw >> 2, kc = csw & 3;

    const unsigned short* asrc0; const unsigned short* asrc1;
    const unsigned short* bsrc0; const unsigned short* bsrc1;
    {
        int r0 = hi * 128 + m, r1 = r0 + 64;
        int lr0 = rt * 256 + r0; if (lr0 >= n_e) lr0 = n_e - 1;
        int lr1 = rt * 256 + r1; if (lr1 >= n_e) lr1 = n_e - 1;
        asrc0 = hbuf + (size_t)(coff + lr0) * I_DIM + kc * 8;
        asrc1 = hbuf + (size_t)(coff + lr1) * I_DIM + kc * 8;
        bsrc0 = w2bf + ((size_t)e * H_DIM + ct * 256 + r0) * I_DIM + kc * 8;
        bsrc1 = w2bf + ((size_t)e * H_DIM + ct * 256 + r1) * I_DIM + kc * 8;
    }

    const int pAoff = (lane & 15) * 64 + ((((wm << 2) | (lane >> 4)) ^ (lane & 7)) << 3);
    const int pBoff = (wn & 1) * 4096 + (lane & 15) * 64 +
                      (((((wn >> 1) << 2) | (lane >> 4)) ^ (lane & 7)) << 3);

    f32x4 acc[8][4] = {};

    GEMM_PIPELINE(I_DIM / 32);                   // NT = 96

    const int rbase = rt * 256 + wm * 128 + (lane >> 4) * 4;
    const int cbase = ct * 256 + wn * 64 + (lane & 15);
#pragma unroll
    for (int i = 0; i < 8; ++i) {
#pragma unroll
        for (int r = 0; r < 4; ++r) {
            const int lr = rbase + i * 16 + r;
            if (lr < n_e) {
                const int token = perm[off + lr];
                const float w = pw[off + lr];
                float* dst = y + (size_t)token * H_DIM + cbase;
#pragma unroll
                for (int j = 0; j < 4; ++j)
                    atomicAdd(dst + j * 16, w * acc[i][j][r]);
            }
        }
    }
}

extern "C" void kernel_launch(void* const* d_in, const int* in_sizes, int n_in,
                              void* d_out, int out_size, void* d_ws, size_t ws_size,
                              hipStream_t stream) {
    const float* x  = (const float*)d_in[0];
    const float* gw = (const float*)d_in[1];
    const float* w1 = (const float*)d_in[2];
    const float* w2 = (const float*)d_in[3];
    float* y = (float*)d_out;  // [N_TOK*H_DIM] + aux at [N_TOK*H_DIM]

    // ---- workspace layout ----
    char* base = (char*)d_ws;
    size_t o = 0;
    unsigned short* xbf  = (unsigned short*)(base + o); o += (size_t)N_TOK * H_DIM * 2;
    unsigned short* w1bf = (unsigned short*)(base + o); o += (size_t)NEXP * I_DIM * H_DIM * 2;
    unsigned short* w2bf = (unsigned short*)(base + o); o += (size_t)NEXP * H_DIM * I_DIM * 2;
    int*   topidx = (int*)(base + o);   o += (size_t)N_TOK * 2 * 4;
    float* topw   = (float*)(base + o); o += (size_t)N_TOK * 2 * 4;
    int*   perm   = (int*)(base + o);   o += (size_t)N_TOK * 2 * 4;
    float* pw     = (float*)(base + o); o += (size_t)N_TOK * 2 * 4;
    float* partials = (float*)(base + o); o += (size_t)RBLK * 16 * 4;
    int*   offs     = (int*)(base + o);   o += 64;
    unsigned short* hbuf = (unsigned short*)(base + o);
    size_t remain = (ws_size > o) ? (ws_size - o) : 0;

    // expert-chunking: hbuf holds full-K h for a group of experts (rows x 3072 bf16).
    long cap_rows = (long)(remain / (size_t)(I_DIM * 2));
    int nch;
    if (cap_rows >= 32768)      nch = 1;
    else if (cap_rows >= 18022) nch = 2;
    else if (cap_rows >= 9011)  nch = 4;
    else                        nch = 8;
    const int G = NEXP / nch;

    hipMemsetAsync(d_out, 0, (size_t)out_size * 4, stream);

    moe_router<<<RBLK, 256, 0, stream>>>(x, gw, xbf, topidx, topw, partials);
    moe_cvt2<<<4096, 256, 0, stream>>>(w1, w1bf, w2, w2bf, NEXP * I_DIM * H_DIM);
    moe_rank<<<RBLK, 256, 0, stream>>>(topidx, topw, partials, offs,
                                       y + (size_t)N_TOK * H_DIM, perm, pw);

    for (int c = 0; c < nch; ++c) {
        const int e0 = c * G;
        moe_gemm1<<<dim3(12, 64, G), 512, 0, stream>>>(
            xbf, w1bf, perm, offs, hbuf, e0);
        moe_gemm2<<<dim3(3, 64, G), 512, 0, stream>>>(
            hbuf, w2bf, perm, pw, offs, y, e0);
    }
}

// Round 13
// 636.596 us; speedup vs baseline: 1.1292x; 1.1292x over previous
//
#include <hip/hip_runtime.h>
#include <hip/hip_bf16.h>

#define N_TOK 16384
#define H_DIM 768
#define I_DIM 3072
#define NEXP 8
#define RBLK 1024   // router grid: 16 contiguous tokens per block; rank depends on this

typedef short bf16x8 __attribute__((ext_vector_type(8)));
typedef float f32x4 __attribute__((ext_vector_type(4)));

__device__ __forceinline__ unsigned short f2bf(float f) {
    unsigned int u = __float_as_uint(f);
    u += 0x7fffu + ((u >> 16) & 1u);
    return (unsigned short)(u >> 16);
}

__device__ __forceinline__ float gelu_tanh(float v) {
    float u = 0.7978845608028654f * (v + 0.044715f * v * v * v);
    float t = __expf(2.0f * fminf(u, 15.0f));
    return 0.5f * v * (1.0f + (t - 1.0f) / (t + 1.0f));
}

__device__ __forceinline__ void gll16(const void* g, void* l) {
    __builtin_amdgcn_global_load_lds(
        (const __attribute__((address_space(1))) unsigned int*)g,
        (__attribute__((address_space(3))) unsigned int*)l, 16, 0, 0);
}

// ---------------- Router: contiguous 16-token strip per block ----------------
__global__ __launch_bounds__(256) void moe_router(
    const float* __restrict__ x, const float* __restrict__ gw,
    unsigned short* __restrict__ xbf,
    int* __restrict__ topidx, float* __restrict__ topw,
    float* __restrict__ partials)
{
    __shared__ float gws[NEXP * H_DIM];  // 24 KB
    __shared__ float red[64];
    const int tid = threadIdx.x;
    for (int i = tid * 4; i < NEXP * H_DIM; i += 1024)
        *(float4*)(gws + i) = *(const float4*)(gw + i);
    __syncthreads();

    const int lane = tid & 63;
    const int wid = tid >> 6;
    const int tbase = blockIdx.x * 16 + wid * 4;

    float lcnt[8], lps[8];
#pragma unroll
    for (int e = 0; e < 8; ++e) { lcnt[e] = 0.f; lps[e] = 0.f; }

#pragma unroll
    for (int k = 0; k < 4; ++k) {
        const int t = tbase + k;
        float acc[8] = {0.f, 0.f, 0.f, 0.f, 0.f, 0.f, 0.f, 0.f};
#pragma unroll
        for (int j = 0; j < 3; ++j) {
            const int col = j * 256 + lane * 4;
            float4 xv = *(const float4*)(x + (size_t)t * H_DIM + col);
            ushort4 o;
            o.x = f2bf(xv.x); o.y = f2bf(xv.y); o.z = f2bf(xv.z); o.w = f2bf(xv.w);
            *(ushort4*)(xbf + (size_t)t * H_DIM + col) = o;
#pragma unroll
            for (int e = 0; e < 8; ++e) {
                float4 g = *(const float4*)(gws + e * H_DIM + col);
                acc[e] += xv.x * g.x + xv.y * g.y + xv.z * g.z + xv.w * g.w;
            }
        }
#pragma unroll
        for (int off = 32; off >= 1; off >>= 1)
#pragma unroll
            for (int e = 0; e < 8; ++e) acc[e] += __shfl_xor(acc[e], off, 64);

        int e0 = 0;
#pragma unroll
        for (int e = 1; e < 8; ++e) if (acc[e] > acc[e0]) e0 = e;
        int e1 = (e0 == 0) ? 1 : 0;
#pragma unroll
        for (int e = 0; e < 8; ++e) if (e != e0 && acc[e] > acc[e1]) e1 = e;

        float mx = acc[0];
#pragma unroll
        for (int e = 1; e < 8; ++e) mx = fmaxf(mx, acc[e]);
        float p[8]; float s = 0.f;
#pragma unroll
        for (int e = 0; e < 8; ++e) { p[e] = expf(acc[e] - mx); s += p[e]; }
        float inv = 1.0f / s;
#pragma unroll
        for (int e = 0; e < 8; ++e) p[e] *= inv;

        float wsum = p[e0] + p[e1];
        if (lane == 0) {
            topidx[2 * t] = e0; topidx[2 * t + 1] = e1;
            topw[2 * t] = p[e0] / wsum; topw[2 * t + 1] = p[e1] / wsum;
            lcnt[e0] += 1.f; lcnt[e1] += 1.f;
#pragma unroll
            for (int e = 0; e < 8; ++e) lps[e] += p[e];
        }
    }

    if (lane == 0) {
#pragma unroll
        for (int e = 0; e < 8; ++e) {
            red[wid * 16 + e] = lcnt[e];
            red[wid * 16 + 8 + e] = lps[e];
        }
    }
    __syncthreads();
    if (tid < 16)
        partials[blockIdx.x * 16 + tid] =
            red[tid] + red[16 + tid] + red[32 + tid] + red[48 + tid];
}

// ------- fused rank (+offsets +aux): one block per 16-token strip -------
__global__ __launch_bounds__(256) void moe_rank(
    const int* __restrict__ topidx, const float* __restrict__ topw,
    const float* __restrict__ partials, int* __restrict__ offs,
    float* __restrict__ aux_out, int* __restrict__ perm, float* __restrict__ pw)
{
    const int b = blockIdx.x;
    const int tid = threadIdx.x;
    __shared__ float stot[256], spre[256];
    __shared__ float tot[16];
    __shared__ int pfx[8];

    const int c = tid & 15;
    float vtot = 0.f, vpre = 0.f;
    for (int r = tid >> 4; r < RBLK; r += 16) {
        float v = partials[r * 16 + c];
        vtot += v;
        if (r < b) vpre += v;
    }
    stot[tid] = vtot; spre[tid] = vpre;
    __syncthreads();
    if (tid < 16) {
        float t = 0.f, q = 0.f;
#pragma unroll
        for (int k = 0; k < 16; ++k) { t += stot[k * 16 + tid]; q += spre[k * 16 + tid]; }
        tot[tid] = t;
        if (tid < 8) spre[tid] = q;   // reuse: per-expert prefix for this strip
    }
    __syncthreads();
    if (tid == 0) {
        int run = 0;
        float aux = 0.f;
#pragma unroll
        for (int e = 0; e < 8; ++e) {
            pfx[e] = run + (int)(spre[e] + 0.5f);
            aux += (tot[e] / (float)(N_TOK * 2)) * (tot[8 + e] / (float)N_TOK);
            if (b == 0) offs[e] = run;
            run += (int)(tot[e] + 0.5f);
        }
        if (b == 0) { offs[8] = run; *aux_out = 0.01f * 8.0f * aux; }
    }
    __syncthreads();
    if (tid < 32) {
        const int t = b * 16 + (tid >> 1);
        const int slot = tid & 1;
        const int myexp = topidx[2 * t + slot];
        int rank = 0;
#pragma unroll
        for (int ee = 0; ee < 8; ++ee) {
            unsigned long long m = __ballot(myexp == ee);
            if (myexp == ee)
                rank = pfx[ee] + __popcll(m & ((1ull << tid) - 1ull));
        }
        perm[rank] = t;
        pw[rank] = topw[2 * t + slot];
    }
}

// ---------------- fused fp32 -> bf16 convert of w1 and w2 ----------------
__global__ __launch_bounds__(256) void moe_cvt2(
    const float* __restrict__ a, unsigned short* __restrict__ oa,
    const float* __restrict__ bsrc, unsigned short* __restrict__ ob, int n)
{
    int idx = (blockIdx.x * 256 + threadIdx.x) * 4;
    const int stride = gridDim.x * 1024;
    for (; idx < 2 * n; idx += stride) {
        const float* in = (idx < n) ? a : bsrc;
        unsigned short* out = (idx < n) ? oa : ob;
        const int i = (idx < n) ? idx : idx - n;
        float4 v = *(const float4*)(in + i);
        ushort4 o;
        o.x = f2bf(v.x); o.y = f2bf(v.y); o.z = f2bf(v.z); o.w = f2bf(v.w);
        *(ushort4*)(out + i) = o;
    }
}

// ====== 256x128 / 4-wave / BK=32 / 3-slot counted-vmcnt GEMM core (2 blk/CU) ======
// Occupancy lever: LDS = 3*(16+8) KB = 72 KB -> 2 blocks/CU, 16 waves/CU.
// A slot 16 KB: logical (r in [0,256), k in [0,32)): L=r&127, c=(r>>7)*4+(k>>3),
// pos p = c ^ (L&7), addr = L*64 + p*8 shorts (R10-verified algebra).
// B slot 8 KB: (r in [0,128)): L=r&63, c=(r>>6)*4+(k>>3), p=c^(L&7) (R9-verified).
// Stage (256 thr): A 4 gll16 rounds q: L=q*32+(tid>>3), p=tid&7 -> src row
// hi*128+q*32+m, chunk kc; B 2 rounds: src row hi*64+q*32+m. hi=csw>>2, kc=csw&3,
// csw=(tid&7)^((tid>>3)&7), m=tid>>3.
// Schedule (R10-verified family): LOADFRAG(t) -> STAGE(t+2) -> MFMA -> vmcnt(6)
// -> barrier. vmcnt(6) leaves only tile t+2 in flight (retires t+1 before its
// reads). Stage writes slot (t+2)%3 = (t-1)%3 whose reads completed before the
// iter-(t-1) barrier. Tail: vmcnt(0) then none. Never vmcnt(0) in main loop.

#define MFMA_(d_, va_, vb_) d_ = __builtin_amdgcn_mfma_f32_16x16x32_bf16(va_, vb_, d_, 0, 0, 0)
#define BAR asm volatile("s_barrier" ::: "memory")
#define SCHED0 __builtin_amdgcn_sched_barrier(0)
#define VM6 asm volatile("s_waitcnt vmcnt(6)" ::: "memory")
#define VM0 asm volatile("s_waitcnt vmcnt(0)" ::: "memory")
#define VMNONE (void)0
#define STAGENONE (void)0

#define STAGE6(tt) { unsigned short* DA_ = As + ((tt) % 3) * 8192;                \
      unsigned short* DB_ = Bs + ((tt) % 3) * 4096;                               \
      gll16(asrc0 + (tt) * 32, DA_ +        tid * 8);                             \
      gll16(asrc1 + (tt) * 32, DA_ + 2048 + tid * 8);                             \
      gll16(asrc2 + (tt) * 32, DA_ + 4096 + tid * 8);                             \
      gll16(asrc3 + (tt) * 32, DA_ + 6144 + tid * 8);                             \
      gll16(bsrc0 + (tt) * 32, DB_ +        tid * 8);                             \
      gll16(bsrc1 + (tt) * 32, DB_ + 2048 + tid * 8); }

#define GEMM_TILE(t, STAGE_OP, VM_OP)                                             \
  { const unsigned short* Ab_ = As + ((t) % 3) * 8192 + pAoff;                    \
    const unsigned short* Bb_ = Bs + ((t) % 3) * 4096 + pBoff;                    \
    bf16x8 a_[8], b_[4];                                                          \
    _Pragma("unroll")                                                             \
    for (int i_ = 0; i_ < 8; ++i_) a_[i_] = *(const bf16x8*)(Ab_ + i_ * 1024);    \
    _Pragma("unroll")                                                             \
    for (int j_ = 0; j_ < 4; ++j_) b_[j_] = *(const bf16x8*)(Bb_ + j_ * 1024);    \
    STAGE_OP;                                                                     \
    __builtin_amdgcn_s_setprio(1);                                                \
    _Pragma("unroll")                                                             \
    for (int i_ = 0; i_ < 8; ++i_)                                                \
    _Pragma("unroll")                                                             \
    for (int j_ = 0; j_ < 4; ++j_)                                                \
        MFMA_(acc[i_][j_], a_[i_], b_[j_]);                                       \
    __builtin_amdgcn_s_setprio(0);                                                \
    VM_OP; BAR; SCHED0; }

#define GEMM_PIPELINE(NT)                                                         \
    STAGE6(0); STAGE6(1);                                                         \
    VM6; BAR;                                                                     \
    for (int t = 0; t < (NT) - 2; ++t) GEMM_TILE(t, STAGE6(t + 2), VM6);          \
    GEMM_TILE((NT) - 2, STAGENONE, VM0);                                          \
    GEMM_TILE((NT) - 1, STAGENONE, VMNONE);

// ---------------- GEMM1: h = gelu(gather(x) @ w1[e]^T) -> hbuf [rows][3072] ----
__global__ __launch_bounds__(256, 2) void moe_gemm1(
    const unsigned short* __restrict__ xbf,
    const unsigned short* __restrict__ w1bf,
    const int* __restrict__ perm, const int* __restrict__ offs,
    unsigned short* __restrict__ hbuf, int e0)
{
    const int e = e0 + blockIdx.z;
    const int off = offs[e];
    const int n_e = offs[e + 1] - off;
    const int rt = blockIdx.y;
    if (rt * 256 >= n_e) return;
    const int ct = blockIdx.x;                   // 0..23
    const int coff = off - offs[e0];

    __shared__ __align__(16) unsigned short As[3 * 8192];  // 48 KB
    __shared__ __align__(16) unsigned short Bs[3 * 4096];  // 24 KB

    const int tid = threadIdx.x;
    const int lane = tid & 63;
    const int wid = tid >> 6;
    const int wm = wid >> 1, wn = wid & 1;       // wave tile 128x64

    // staging geometry
    const int m = tid >> 3;                      // 0..31
    const int csw = (tid & 7) ^ (m & 7);
    const int hi = csw >> 2, kc = csw & 3;

    const unsigned short *asrc0, *asrc1, *asrc2, *asrc3, *bsrc0, *bsrc1;
    {
        const unsigned short* aq[4];
#pragma unroll
        for (int q = 0; q < 4; ++q) {
            int r = rt * 256 + hi * 128 + q * 32 + m;
            if (r >= n_e + rt * 256) {}          // (row index is block-relative clamp below)
            int lr = rt * 256 + hi * 128 + q * 32 + m;
            if (lr >= n_e) lr = n_e - 1;
            aq[q] = xbf + (size_t)perm[off + lr] * H_DIM + kc * 8;
        }
        asrc0 = aq[0]; asrc1 = aq[1]; asrc2 = aq[2]; asrc3 = aq[3];
        const size_t wb = (size_t)e * I_DIM + ct * 128 + hi * 64;
        bsrc0 = w1bf + (wb +  0 + m) * H_DIM + kc * 8;
        bsrc1 = w1bf + (wb + 32 + m) * H_DIM + kc * 8;
    }

    const int pAoff = (lane & 15) * 64 + ((((wm << 2) | (lane >> 4)) ^ (lane & 7)) << 3);
    const int pBoff = (lane & 15) * 64 + ((((wn << 2) | (lane >> 4)) ^ (lane & 7)) << 3);

    f32x4 acc[8][4] = {};

    GEMM_PIPELINE(H_DIM / 32);                   // NT = 24

    const int rbase = rt * 256 + wm * 128 + (lane >> 4) * 4;
    const int cbase = ct * 128 + wn * 64 + (lane & 15);
#pragma unroll
    for (int i = 0; i < 8; ++i) {
#pragma unroll
        for (int r = 0; r < 4; ++r) {
            const int lr = rbase + i * 16 + r;
            if (lr < n_e) {
                unsigned short* dst = hbuf + (size_t)(coff + lr) * I_DIM + cbase;
#pragma unroll
                for (int j = 0; j < 4; ++j)
                    dst[j * 16] = f2bf(gelu_tanh(acc[i][j][r]));
            }
        }
    }
}

// ---------------- GEMM2: y += w * (h @ w2[e]^T), full K=3072 ----------------
__global__ __launch_bounds__(256, 2) void moe_gemm2(
    const unsigned short* __restrict__ hbuf,
    const unsigned short* __restrict__ w2bf,
    const int* __restrict__ perm, const float* __restrict__ pw,
    const int* __restrict__ offs, float* __restrict__ y, int e0)
{
    const int e = e0 + blockIdx.z;
    const int off = offs[e];
    const int n_e = offs[e + 1] - off;
    const int rt = blockIdx.y;
    if (rt * 256 >= n_e) return;
    const int ct = blockIdx.x;                   // 0..5
    const int coff = off - offs[e0];

    __shared__ __align__(16) unsigned short As[3 * 8192];
    __shared__ __align__(16) unsigned short Bs[3 * 4096];

    const int tid = threadIdx.x;
    const int lane = tid & 63;
    const int wid = tid >> 6;
    const int wm = wid >> 1, wn = wid & 1;

    const int m = tid >> 3;
    const int csw = (tid & 7) ^ (m & 7);
    const int hi = csw >> 2, kc = csw & 3;

    const unsigned short *asrc0, *asrc1, *asrc2, *asrc3, *bsrc0, *bsrc1;
    {
        const unsigned short* aq[4];
#pragma unroll
        for (int q = 0; q < 4; ++q) {
            int lr = rt * 256 + hi * 128 + q * 32 + m;
            if (lr >= n_e) lr = n_e - 1;
            aq[q] = hbuf + (size_t)(coff + lr) * I_DIM + kc * 8;
        }
        asrc0 = aq[0]; asrc1 = aq[1]; asrc2 = aq[2]; asrc3 = aq[3];
        const size_t wb = (size_t)e * H_DIM + ct * 128 + hi * 64;
        bsrc0 = w2bf + (wb +  0 + m) * I_DIM + kc * 8;
        bsrc1 = w2bf + (wb + 32 + m) * I_DIM + kc * 8;
    }

    const int pAoff = (lane & 15) * 64 + ((((wm << 2) | (lane >> 4)) ^ (lane & 7)) << 3);
    const int pBoff = (lane & 15) * 64 + ((((wn << 2) | (lane >> 4)) ^ (lane & 7)) << 3);

    f32x4 acc[8][4] = {};

    GEMM_PIPELINE(I_DIM / 32);                   // NT = 96

    const int rbase = rt * 256 + wm * 128 + (lane >> 4) * 4;
    const int cbase = ct * 128 + wn * 64 + (lane & 15);
#pragma unroll
    for (int i = 0; i < 8; ++i) {
#pragma unroll
        for (int r = 0; r < 4; ++r) {
            const int lr = rbase + i * 16 + r;
            if (lr < n_e) {
                const int token = perm[off + lr];
                const float w = pw[off + lr];
                float* dst = y + (size_t)token * H_DIM + cbase;
#pragma unroll
                for (int j = 0; j < 4; ++j)
                    atomicAdd(dst + j * 16, w * acc[i][j][r]);
            }
        }
    }
}

extern "C" void kernel_launch(void* const* d_in, const int* in_sizes, int n_in,
                              void* d_out, int out_size, void* d_ws, size_t ws_size,
                              hipStream_t stream) {
    const float* x  = (const float*)d_in[0];
    const float* gw = (const float*)d_in[1];
    const float* w1 = (const float*)d_in[2];
    const float* w2 = (const float*)d_in[3];
    float* y = (float*)d_out;  // [N_TOK*H_DIM] + aux at [N_TOK*H_DIM]

    // ---- workspace layout ----
    char* base = (char*)d_ws;
    size_t o = 0;
    unsigned short* xbf  = (unsigned short*)(base + o); o += (size_t)N_TOK * H_DIM * 2;
    unsigned short* w1bf = (unsigned short*)(base + o); o += (size_t)NEXP * I_DIM * H_DIM * 2;
    unsigned short* w2bf = (unsigned short*)(base + o); o += (size_t)NEXP * H_DIM * I_DIM * 2;
    int*   topidx = (int*)(base + o);   o += (size_t)N_TOK * 2 * 4;
    float* topw   = (float*)(base + o); o += (size_t)N_TOK * 2 * 4;
    int*   perm   = (int*)(base + o);   o += (size_t)N_TOK * 2 * 4;
    float* pw     = (float*)(base + o); o += (size_t)N_TOK * 2 * 4;
    float* partials = (float*)(base + o); o += (size_t)RBLK * 16 * 4;
    int*   offs     = (int*)(base + o);   o += 64;
    unsigned short* hbuf = (unsigned short*)(base + o);
    size_t remain = (ws_size > o) ? (ws_size - o) : 0;

    // expert-chunking: hbuf holds full-K h for a group of experts (rows x 3072 bf16).
    long cap_rows = (long)(remain / (size_t)(I_DIM * 2));
    int nch;
    if (cap_rows >= 32768)      nch = 1;
    else if (cap_rows >= 18022) nch = 2;
    else if (cap_rows >= 9011)  nch = 4;
    else                        nch = 8;
    const int G = NEXP / nch;

    hipMemsetAsync(d_out, 0, (size_t)out_size * 4, stream);

    moe_router<<<RBLK, 256, 0, stream>>>(x, gw, xbf, topidx, topw, partials);
    moe_cvt2<<<4096, 256, 0, stream>>>(w1, w1bf, w2, w2bf, NEXP * I_DIM * H_DIM);
    moe_rank<<<RBLK, 256, 0, stream>>>(topidx, topw, partials, offs,
                                       y + (size_t)N_TOK * H_DIM, perm, pw);

    for (int c = 0; c < nch; ++c) {
        const int e0 = c * G;
        moe_gemm1<<<dim3(24, 64, G), 256, 0, stream>>>(
            xbf, w1bf, perm, offs, hbuf, e0);
        moe_gemm2<<<dim3(6, 64, G), 256, 0, stream>>>(
            hbuf, w2bf, perm, pw, offs, y, e0);
    }
}

// Round 15
// 598.830 us; speedup vs baseline: 1.2004x; 1.0631x over previous
//
#include <hip/hip_runtime.h>
#include <hip/hip_bf16.h>

#define N_TOK 16384
#define H_DIM 768
#define I_DIM 3072
#define NEXP 8
#define RBLK 1024   // router grid: 16 contiguous tokens per block; rank depends on this

typedef short bf16x8 __attribute__((ext_vector_type(8)));
typedef float f32x4 __attribute__((ext_vector_type(4)));

__device__ __forceinline__ unsigned short f2bf(float f) {
    unsigned int u = __float_as_uint(f);
    u += 0x7fffu + ((u >> 16) & 1u);
    return (unsigned short)(u >> 16);
}

__device__ __forceinline__ float gelu_tanh(float v) {
    float u = 0.7978845608028654f * (v + 0.044715f * v * v * v);
    float t = __expf(2.0f * fminf(u, 15.0f));
    return 0.5f * v * (1.0f + (t - 1.0f) / (t + 1.0f));
}

__device__ __forceinline__ void gll16(const void* g, void* l) {
    __builtin_amdgcn_global_load_lds(
        (const __attribute__((address_space(1))) unsigned int*)g,
        (__attribute__((address_space(3))) unsigned int*)l, 16, 0, 0);
}

// ---------------- Router: contiguous 16-token strip per block ----------------
__global__ __launch_bounds__(256) void moe_router(
    const float* __restrict__ x, const float* __restrict__ gw,
    unsigned short* __restrict__ xbf,
    int* __restrict__ topidx, float* __restrict__ topw,
    float* __restrict__ partials)
{
    __shared__ float gws[NEXP * H_DIM];  // 24 KB
    __shared__ float red[64];
    const int tid = threadIdx.x;
    for (int i = tid * 4; i < NEXP * H_DIM; i += 1024)
        *(float4*)(gws + i) = *(const float4*)(gw + i);
    __syncthreads();

    const int lane = tid & 63;
    const int wid = tid >> 6;
    const int tbase = blockIdx.x * 16 + wid * 4;

    float lcnt[8], lps[8];
#pragma unroll
    for (int e = 0; e < 8; ++e) { lcnt[e] = 0.f; lps[e] = 0.f; }

#pragma unroll
    for (int k = 0; k < 4; ++k) {
        const int t = tbase + k;
        float acc[8] = {0.f, 0.f, 0.f, 0.f, 0.f, 0.f, 0.f, 0.f};
#pragma unroll
        for (int j = 0; j < 3; ++j) {
            const int col = j * 256 + lane * 4;
            float4 xv = *(const float4*)(x + (size_t)t * H_DIM + col);
            ushort4 o;
            o.x = f2bf(xv.x); o.y = f2bf(xv.y); o.z = f2bf(xv.z); o.w = f2bf(xv.w);
            *(ushort4*)(xbf + (size_t)t * H_DIM + col) = o;
#pragma unroll
            for (int e = 0; e < 8; ++e) {
                float4 g = *(const float4*)(gws + e * H_DIM + col);
                acc[e] += xv.x * g.x + xv.y * g.y + xv.z * g.z + xv.w * g.w;
            }
        }
#pragma unroll
        for (int off = 32; off >= 1; off >>= 1)
#pragma unroll
            for (int e = 0; e < 8; ++e) acc[e] += __shfl_xor(acc[e], off, 64);

        int e0 = 0;
#pragma unroll
        for (int e = 1; e < 8; ++e) if (acc[e] > acc[e0]) e0 = e;
        int e1 = (e0 == 0) ? 1 : 0;
#pragma unroll
        for (int e = 0; e < 8; ++e) if (e != e0 && acc[e] > acc[e1]) e1 = e;

        float mx = acc[0];
#pragma unroll
        for (int e = 1; e < 8; ++e) mx = fmaxf(mx, acc[e]);
        float p[8]; float s = 0.f;
#pragma unroll
        for (int e = 0; e < 8; ++e) { p[e] = expf(acc[e] - mx); s += p[e]; }
        float inv = 1.0f / s;
#pragma unroll
        for (int e = 0; e < 8; ++e) p[e] *= inv;

        float wsum = p[e0] + p[e1];
        if (lane == 0) {
            topidx[2 * t] = e0; topidx[2 * t + 1] = e1;
            topw[2 * t] = p[e0] / wsum; topw[2 * t + 1] = p[e1] / wsum;
            lcnt[e0] += 1.f; lcnt[e1] += 1.f;
#pragma unroll
            for (int e = 0; e < 8; ++e) lps[e] += p[e];
        }
    }

    if (lane == 0) {
#pragma unroll
        for (int e = 0; e < 8; ++e) {
            red[wid * 16 + e] = lcnt[e];
            red[wid * 16 + 8 + e] = lps[e];
        }
    }
    __syncthreads();
    if (tid < 16)
        partials[blockIdx.x * 16 + tid] =
            red[tid] + red[16 + tid] + red[32 + tid] + red[48 + tid];
}

// ------- fused rank (+offsets +aux): one block per 16-token strip -------
__global__ __launch_bounds__(256) void moe_rank(
    const int* __restrict__ topidx, const float* __restrict__ topw,
    const float* __restrict__ partials, int* __restrict__ offs,
    float* __restrict__ aux_out, int* __restrict__ perm, float* __restrict__ pw)
{
    const int b = blockIdx.x;
    const int tid = threadIdx.x;
    __shared__ float stot[256], spre[256];
    __shared__ float tot[16];
    __shared__ int pfx[8];

    const int c = tid & 15;
    float vtot = 0.f, vpre = 0.f;
    for (int r = tid >> 4; r < RBLK; r += 16) {
        float v = partials[r * 16 + c];
        vtot += v;
        if (r < b) vpre += v;
    }
    stot[tid] = vtot; spre[tid] = vpre;
    __syncthreads();
    if (tid < 16) {
        float t = 0.f, q = 0.f;
#pragma unroll
        for (int k = 0; k < 16; ++k) { t += stot[k * 16 + tid]; q += spre[k * 16 + tid]; }
        tot[tid] = t;
        if (tid < 8) spre[tid] = q;   // reuse: per-expert prefix for this strip
    }
    __syncthreads();
    if (tid == 0) {
        int run = 0;
        float aux = 0.f;
#pragma unroll
        for (int e = 0; e < 8; ++e) {
            pfx[e] = run + (int)(spre[e] + 0.5f);
            aux += (tot[e] / (float)(N_TOK * 2)) * (tot[8 + e] / (float)N_TOK);
            if (b == 0) offs[e] = run;
            run += (int)(tot[e] + 0.5f);
        }
        if (b == 0) { offs[8] = run; *aux_out = 0.01f * 8.0f * aux; }
    }
    __syncthreads();
    if (tid < 32) {
        const int t = b * 16 + (tid >> 1);
        const int slot = tid & 1;
        const int myexp = topidx[2 * t + slot];
        int rank = 0;
#pragma unroll
        for (int ee = 0; ee < 8; ++ee) {
            unsigned long long m = __ballot(myexp == ee);
            if (myexp == ee)
                rank = pfx[ee] + __popcll(m & ((1ull << tid) - 1ull));
        }
        perm[rank] = t;
        pw[rank] = topw[2 * t + slot];
    }
}

// ---------------- fused fp32 -> bf16 convert of w1 and w2 ----------------
__global__ __launch_bounds__(256) void moe_cvt2(
    const float* __restrict__ a, unsigned short* __restrict__ oa,
    const float* __restrict__ bsrc, unsigned short* __restrict__ ob, int n)
{
    int idx = (blockIdx.x * 256 + threadIdx.x) * 4;
    const int stride = gridDim.x * 1024;
    for (; idx < 2 * n; idx += stride) {
        const float* in = (idx < n) ? a : bsrc;
        unsigned short* out = (idx < n) ? oa : ob;
        const int i = (idx < n) ? idx : idx - n;
        float4 v = *(const float4*)(in + i);
        ushort4 o;
        o.x = f2bf(v.x); o.y = f2bf(v.y); o.z = f2bf(v.z); o.w = f2bf(v.w);
        *(ushort4*)(out + i) = o;
    }
}

// ============ 256x256 / 8-wave / BK=32 / 4-slot counted-vmcnt GEMM core ============
// (R10-verified: best measured configuration this session, 603 us wall.)
// Geometry: block 256x256, 512 threads, wave tile 128x64 (wm=wid>>2, wn=wid&3).
// LDS slot (16 KB each, A and B): packed [128 L][64 shorts]: logical row r (0..255),
// k (0..31): L = r&127, chunk c = (r>>7)*4 + (k>>3), pos p = c ^ (L&7).
// Stage: 4 gll16/thread (2 A + 2 B); load q covers L = q*64 + (tid>>3), p = tid&7
//  -> source r = hi*128 + q*64 + (tid>>3), k-chunk kc, with c=(tid&7)^((tid>>3)&7).
// Schedule (R9-verified race-free): LOADFRAG(t) -> STAGE(t+3) -> MFMA -> vmcnt(8)
// -> barrier. Stage writes slot (t+3)&3 = (t-1)&3 whose reads completed before the
// iter-(t-1) barrier; vmcnt(8) retires tile t+1. Tail peels 4 -> 0.

#define GEMM_STAGE(t)                                                             \
    { const int s_ = (t) & 3;                                                     \
      gll16(asrc0 + (t) * 32, As + s_ * 8192 +        tid * 8);                   \
      gll16(asrc1 + (t) * 32, As + s_ * 8192 + 4096 + tid * 8);                   \
      gll16(bsrc0 + (t) * 32, Bs + s_ * 8192 +        tid * 8);                   \
      gll16(bsrc1 + (t) * 32, Bs + s_ * 8192 + 4096 + tid * 8); }

#define GEMM_LOADFRAG(t)                                                          \
      const unsigned short* Ab_ = As + ((t) & 3) * 8192 + pAoff;                  \
      const unsigned short* Bb_ = Bs + ((t) & 3) * 8192 + pBoff;                  \
      bf16x8 a_[8], b_[4];                                                        \
      _Pragma("unroll")                                                           \
      for (int i_ = 0; i_ < 8; ++i_) a_[i_] = *(const bf16x8*)(Ab_ + i_ * 1024);  \
      _Pragma("unroll")                                                           \
      for (int j_ = 0; j_ < 4; ++j_) b_[j_] = *(const bf16x8*)(Bb_ + j_ * 1024);

#define GEMM_MFMA()                                                               \
      __builtin_amdgcn_s_setprio(1);                                              \
      _Pragma("unroll")                                                           \
      for (int i_ = 0; i_ < 8; ++i_)                                              \
      _Pragma("unroll")                                                           \
      for (int j_ = 0; j_ < 4; ++j_)                                              \
          acc[i_][j_] = __builtin_amdgcn_mfma_f32_16x16x32_bf16(                  \
              a_[i_], b_[j_], acc[i_][j_], 0, 0, 0);                              \
      __builtin_amdgcn_s_setprio(0);

#define GEMM_SYNC(N_IMM)                                                          \
    asm volatile("s_waitcnt vmcnt(" #N_IMM ")" ::: "memory");                     \
    __builtin_amdgcn_s_barrier();                                                 \
    __builtin_amdgcn_sched_barrier(0);

#define GEMM_PIPELINE(NT)                                                         \
    GEMM_STAGE(0); GEMM_STAGE(1); GEMM_STAGE(2);                                  \
    GEMM_SYNC(8);                                                                 \
    for (int t = 0; t < (NT) - 3; ++t) {                                          \
        GEMM_LOADFRAG(t);                                                         \
        GEMM_STAGE(t + 3);                                                        \
        GEMM_MFMA();                                                              \
        GEMM_SYNC(8);                                                             \
    }                                                                             \
    { GEMM_LOADFRAG((NT) - 3); GEMM_MFMA(); }                                     \
    GEMM_SYNC(4);                                                                 \
    { GEMM_LOADFRAG((NT) - 2); GEMM_MFMA(); }                                     \
    GEMM_SYNC(0);                                                                 \
    { GEMM_LOADFRAG((NT) - 1); GEMM_MFMA(); }

// ---------------- GEMM1: h = gelu(gather(x) @ w1[e]^T) -> hbuf [rows][3072] ----
__global__ __launch_bounds__(512) void moe_gemm1(
    const unsigned short* __restrict__ xbf,
    const unsigned short* __restrict__ w1bf,
    const int* __restrict__ perm, const int* __restrict__ offs,
    unsigned short* __restrict__ hbuf, int e0)
{
    const int e = e0 + blockIdx.z;
    const int off = offs[e];
    const int n_e = offs[e + 1] - off;
    const int rt = blockIdx.y;
    if (rt * 256 >= n_e) return;
    const int ct = blockIdx.x;                   // 0..11
    const int coff = off - offs[e0];

    __shared__ __align__(16) unsigned short As[4 * 8192];  // 64 KB
    __shared__ __align__(16) unsigned short Bs[4 * 8192];  // 64 KB

    const int tid = threadIdx.x;
    const int lane = tid & 63;
    const int wid = tid >> 6;
    const int wm = wid >> 2, wn = wid & 3;       // wave tile 128x64

    // staging geometry
    const int m = tid >> 3;                      // 0..63
    const int csw = (tid & 7) ^ (m & 7);
    const int hi = csw >> 2, kc = csw & 3;

    const unsigned short* asrc0; const unsigned short* asrc1;
    const unsigned short* bsrc0; const unsigned short* bsrc1;
    {
        int r0 = hi * 128 + m, r1 = r0 + 64;
        int lr0 = rt * 256 + r0; if (lr0 >= n_e) lr0 = n_e - 1;
        int lr1 = rt * 256 + r1; if (lr1 >= n_e) lr1 = n_e - 1;
        asrc0 = xbf + (size_t)perm[off + lr0] * H_DIM + kc * 8;
        asrc1 = xbf + (size_t)perm[off + lr1] * H_DIM + kc * 8;
        bsrc0 = w1bf + ((size_t)e * I_DIM + ct * 256 + r0) * H_DIM + kc * 8;
        bsrc1 = w1bf + ((size_t)e * I_DIM + ct * 256 + r1) * H_DIM + kc * 8;
    }

    const int pAoff = (lane & 15) * 64 + ((((wm << 2) | (lane >> 4)) ^ (lane & 7)) << 3);
    const int pBoff = (wn & 1) * 4096 + (lane & 15) * 64 +
                      (((((wn >> 1) << 2) | (lane >> 4)) ^ (lane & 7)) << 3);

    f32x4 acc[8][4] = {};

    GEMM_PIPELINE(H_DIM / 32);                   // NT = 24

    const int rbase = rt * 256 + wm * 128 + (lane >> 4) * 4;
    const int cbase = ct * 256 + wn * 64 + (lane & 15);
#pragma unroll
    for (int i = 0; i < 8; ++i) {
#pragma unroll
        for (int r = 0; r < 4; ++r) {
            const int lr = rbase + i * 16 + r;
            if (lr < n_e) {
                unsigned short* dst = hbuf + (size_t)(coff + lr) * I_DIM + cbase;
#pragma unroll
                for (int j = 0; j < 4; ++j)
                    dst[j * 16] = f2bf(gelu_tanh(acc[i][j][r]));
            }
        }
    }
}

// ---------------- GEMM2: y += w * (h @ w2[e]^T), full K=3072 ----------------
__global__ __launch_bounds__(512) void moe_gemm2(
    const unsigned short* __restrict__ hbuf,
    const unsigned short* __restrict__ w2bf,
    const int* __restrict__ perm, const float* __restrict__ pw,
    const int* __restrict__ offs, float* __restrict__ y, int e0)
{
    const int e = e0 + blockIdx.z;
    const int off = offs[e];
    const int n_e = offs[e + 1] - off;
    const int rt = blockIdx.y;
    if (rt * 256 >= n_e) return;
    const int ct = blockIdx.x;                   // 0..2
    const int coff = off - offs[e0];

    __shared__ __align__(16) unsigned short As[4 * 8192];
    __shared__ __align__(16) unsigned short Bs[4 * 8192];

    const int tid = threadIdx.x;
    const int lane = tid & 63;
    const int wid = tid >> 6;
    const int wm = wid >> 2, wn = wid & 3;

    const int m = tid >> 3;
    const int csw = (tid & 7) ^ (m & 7);
    const int hi = csw >> 2, kc = csw & 3;

    const unsigned short* asrc0; const unsigned short* asrc1;
    const unsigned short* bsrc0; const unsigned short* bsrc1;
    {
        int r0 = hi * 128 + m, r1 = r0 + 64;
        int lr0 = rt * 256 + r0; if (lr0 >= n_e) lr0 = n_e - 1;
        int lr1 = rt * 256 + r1; if (lr1 >= n_e) lr1 = n_e - 1;
        asrc0 = hbuf + (size_t)(coff + lr0) * I_DIM + kc * 8;
        asrc1 = hbuf + (size_t)(coff + lr1) * I_DIM + kc * 8;
        bsrc0 = w2bf + ((size_t)e * H_DIM + ct * 256 + r0) * I_DIM + kc * 8;
        bsrc1 = w2bf + ((size_t)e * H_DIM + ct * 256 + r1) * I_DIM + kc * 8;
    }

    const int pAoff = (lane & 15) * 64 + ((((wm << 2) | (lane >> 4)) ^ (lane & 7)) << 3);
    const int pBoff = (wn & 1) * 4096 + (lane & 15) * 64 +
                      (((((wn >> 1) << 2) | (lane >> 4)) ^ (lane & 7)) << 3);

    f32x4 acc[8][4] = {};

    GEMM_PIPELINE(I_DIM / 32);                   // NT = 96

    const int rbase = rt * 256 + wm * 128 + (lane >> 4) * 4;
    const int cbase = ct * 256 + wn * 64 + (lane & 15);
#pragma unroll
    for (int i = 0; i < 8; ++i) {
#pragma unroll
        for (int r = 0; r < 4; ++r) {
            const int lr = rbase + i * 16 + r;
            if (lr < n_e) {
                const int token = perm[off + lr];
                const float w = pw[off + lr];
                float* dst = y + (size_t)token * H_DIM + cbase;
#pragma unroll
                for (int j = 0; j < 4; ++j)
                    atomicAdd(dst + j * 16, w * acc[i][j][r]);
            }
        }
    }
}

extern "C" void kernel_launch(void* const* d_in, const int* in_sizes, int n_in,
                              void* d_out, int out_size, void* d_ws, size_t ws_size,
                              hipStream_t stream) {
    const float* x  = (const float*)d_in[0];
    const float* gw = (const float*)d_in[1];
    const float* w1 = (const float*)d_in[2];
    const float* w2 = (const float*)d_in[3];
    float* y = (float*)d_out;  // [N_TOK*H_DIM] + aux at [N_TOK*H_DIM]

    // ---- workspace layout ----
    char* base = (char*)d_ws;
    size_t o = 0;
    unsigned short* xbf  = (unsigned short*)(base + o); o += (size_t)N_TOK * H_DIM * 2;
    unsigned short* w1bf = (unsigned short*)(base + o); o += (size_t)NEXP * I_DIM * H_DIM * 2;
    unsigned short* w2bf = (unsigned short*)(base + o); o += (size_t)NEXP * H_DIM * I_DIM * 2;
    int*   topidx = (int*)(base + o);   o += (size_t)N_TOK * 2 * 4;
    float* topw   = (float*)(base + o); o += (size_t)N_TOK * 2 * 4;
    int*   perm   = (int*)(base + o);   o += (size_t)N_TOK * 2 * 4;
    float* pw     = (float*)(base + o); o += (size_t)N_TOK * 2 * 4;
    float* partials = (float*)(base + o); o += (size_t)RBLK * 16 * 4;
    int*   offs     = (int*)(base + o);   o += 64;
    unsigned short* hbuf = (unsigned short*)(base + o);
    size_t remain = (ws_size > o) ? (ws_size - o) : 0;

    // expert-chunking: hbuf holds full-K h for a group of experts (rows x 3072 bf16).
    long cap_rows = (long)(remain / (size_t)(I_DIM * 2));
    int nch;
    if (cap_rows >= 32768)      nch = 1;
    else if (cap_rows >= 18022) nch = 2;
    else if (cap_rows >= 9011)  nch = 4;
    else                        nch = 8;
    const int G = NEXP / nch;

    hipMemsetAsync(d_out, 0, (size_t)out_size * 4, stream);

    moe_router<<<RBLK, 256, 0, stream>>>(x, gw, xbf, topidx, topw, partials);
    moe_cvt2<<<4096, 256, 0, stream>>>(w1, w1bf, w2, w2bf, NEXP * I_DIM * H_DIM);
    moe_rank<<<RBLK, 256, 0, stream>>>(topidx, topw, partials, offs,
                                       y + (size_t)N_TOK * H_DIM, perm, pw);

    for (int c = 0; c < nch; ++c) {
        const int e0 = c * G;
        moe_gemm1<<<dim3(12, 64, G), 512, 0, stream>>>(
            xbf, w1bf, perm, offs, hbuf, e0);
        moe_gemm2<<<dim3(3, 64, G), 512, 0, stream>>>(
            hbuf, w2bf, perm, pw, offs, y, e0);
    }
}